// Round 16
// baseline (145.516 us; speedup 1.0000x reference)
//
#include <hip/hip_runtime.h>

typedef _Float16 f16;
typedef _Float16 f16x2 __attribute__((ext_vector_type(2)));
typedef _Float16 f16x4 __attribute__((ext_vector_type(4)));
typedef _Float16 f16x8 __attribute__((ext_vector_type(8)));
typedef __fp16   h16x2 __attribute__((ext_vector_type(2)));
typedef float    f32x4 __attribute__((ext_vector_type(4)));
typedef float    f32x16 __attribute__((ext_vector_type(16)));

static constexpr float L2E = 1.44269504088896340736f;
// folded into q-projection: (1/sqrt(64)) * log2(e)
static constexpr float QSC = 0.18033688011112042f;

static __device__ __forceinline__ f32x4 mfma16(f16x8 a, f16x8 b, f32x4 c) {
    return __builtin_amdgcn_mfma_f32_16x16x32_f16(a, b, c, 0, 0, 0);
}
static __device__ __forceinline__ f32x16 mfma32(f16x8 a, f16x8 b, f32x16 c) {
    return __builtin_amdgcn_mfma_f32_32x32x16_f16(a, b, c, 0, 0, 0);
}
static __device__ __forceinline__ f16x2 cvt_pk(float a, float b) {
    h16x2 t = __builtin_amdgcn_cvt_pkrtz(a, b);
    return __builtin_bit_cast(f16x2, t);
}
// async global->LDS DMA, 16B per lane. LDS dest = WAVE-UNIFORM base + lane*16.
static __device__ __forceinline__ void gload16(const void* g, void* l) {
    __builtin_amdgcn_global_load_lds(
        (const __attribute__((address_space(1))) unsigned int*)g,
        (__attribute__((address_space(3))) unsigned int*)l, 16, 0, 0);
}

// ---------------------------------------------------------------------------
// Kernel 0: transpose W [512][64] f32 -> WT [64][512] f16 (per tensor)
// ---------------------------------------------------------------------------
__global__ void ah_wt_prep(const float* __restrict__ Wq,
                           const float* __restrict__ Wk,
                           const float* __restrict__ Wv,
                           f16* __restrict__ WT) {
    const float* W = (blockIdx.x == 0) ? Wq : (blockIdx.x == 1) ? Wk : Wv;
    f16* o = WT + (size_t)blockIdx.x * (64 * 512);
    for (int i = threadIdx.x; i < 64 * 512; i += blockDim.x) {
        int col = i >> 9, e = i & 511;
        o[i] = (f16)W[e * 64 + col];
    }
}

// ---------------------------------------------------------------------------
// Kernel 1: projection  P = X @ W + b  (X fp32 [32768][512] -> out f16).
// R13 verbatim (best measured): DMA barrier-pipeline, DEPTH-3, BK=32,
// 4 buffers x (X 8KB + W 4KB) = 48KB LDS -> 3 blocks/CU. vmcnt(9) steady,
// drain 6/3/0. X XOR-swizzled (unit^=row&7, source-pre-swizzled); W linear.
// grid (512 row-tiles of 64, 3 tensors), block 256 = 4 waves x 16 rows.
// tensor 0 -> qp (scaled QSC), 1 -> kp, 2 -> vpT [b][64][4096]
// ---------------------------------------------------------------------------
__global__ __launch_bounds__(256, 3) void ah_proj(
    const float* __restrict__ Xq, const float* __restrict__ Xk, const float* __restrict__ Xv,
    const float* __restrict__ bq, const float* __restrict__ bk, const float* __restrict__ bv,
    const f16* __restrict__ WT,
    f16* __restrict__ qp, f16* __restrict__ kp, f16* __restrict__ vpT) {

    const int tens = blockIdx.y;
    const float* X    = (tens == 0) ? Xq : (tens == 1) ? Xk : Xv;
    const float* bias = (tens == 0) ? bq : (tens == 1) ? bk : bv;
    const f16* wt = WT + (size_t)tens * (64 * 512);
    const float osc = (tens == 0) ? QSC : 1.0f;

    const int lane = threadIdx.x & 63;
    const int wave = threadIdx.x >> 6;
    const int l15 = lane & 15, g = lane >> 4;
    const int row0 = blockIdx.x * 64;
    const int wrow = wave * 16;

    __shared__ __align__(16) char smem[49152];   // 4 x (X 8KB | W 4KB)

    const int xr8 = lane >> 3;                   // 0..7
    const int xsu = (lane & 7) ^ xr8;            // source unit (pre-swizzled)

#define PSTAGE(KC) do {                                                              \
    char* _xb = smem + ((KC) & 3) * 12288;                                           \
    char* _wb = _xb + 8192;                                                          \
    gload16(X + (size_t)(row0 + wrow + xr8) * 512 + (KC) * 32 + xsu * 4,             \
            _xb + wave * 2048);                                                      \
    gload16(X + (size_t)(row0 + wrow + 8 + xr8) * 512 + (KC) * 32 + xsu * 4,         \
            _xb + wave * 2048 + 1024);                                               \
    gload16(wt + (size_t)(wrow + (lane >> 2)) * 512 + (KC) * 32 + (lane & 3) * 8,    \
            _wb + wave * 1024);                                                      \
} while (0)

    f32x4 acc[4];
#pragma unroll
    for (int b = 0; b < 4; ++b) acc[b] = (f32x4){0.f, 0.f, 0.f, 0.f};

#define PCOMP(KC) do {                                                               \
    const char* _xb = smem + ((KC) & 3) * 12288;                                     \
    const char* _wb = _xb + 8192;                                                    \
    const char* _cb = _xb + (wrow + l15) * 128;                                      \
    float4 v0 = *(const float4*)(_cb + (((2 * g + 0) ^ (l15 & 7)) << 4));            \
    float4 v1 = *(const float4*)(_cb + (((2 * g + 1) ^ (l15 & 7)) << 4));            \
    f16x2 p0 = cvt_pk(v0.x, v0.y), p1 = cvt_pk(v0.z, v0.w);                          \
    f16x2 p2 = cvt_pk(v1.x, v1.y), p3 = cvt_pk(v1.z, v1.w);                          \
    f16x8 a;                                                                         \
    a[0] = p0[0]; a[1] = p0[1]; a[2] = p1[0]; a[3] = p1[1];                          \
    a[4] = p2[0]; a[5] = p2[1]; a[6] = p3[0]; a[7] = p3[1];                          \
    _Pragma("unroll")                                                                \
    for (int cf = 0; cf < 4; ++cf) {                                                 \
        f16x8 bfr = *(const f16x8*)(_wb + (cf * 16 + l15) * 64 + g * 16);            \
        acc[cf] = mfma16(a, bfr, acc[cf]);                                           \
    }                                                                                \
} while (0)

    PSTAGE(0); PSTAGE(1); PSTAGE(2);
    for (int kc = 0; kc < 13; ++kc) {            // steady state: depth-3
        PSTAGE(kc + 3);
        asm volatile("s_waitcnt vmcnt(9)" ::: "memory");
        __builtin_amdgcn_sched_barrier(0);
        __builtin_amdgcn_s_barrier();
        __builtin_amdgcn_sched_barrier(0);
        PCOMP(kc);
        __builtin_amdgcn_sched_barrier(0);
        __builtin_amdgcn_s_barrier();
    }
    // drain: chunks 13,14,15
    asm volatile("s_waitcnt vmcnt(6)" ::: "memory");
    __builtin_amdgcn_sched_barrier(0);
    __builtin_amdgcn_s_barrier();
    PCOMP(13);
    __builtin_amdgcn_s_barrier();
    asm volatile("s_waitcnt vmcnt(3)" ::: "memory");
    __builtin_amdgcn_sched_barrier(0);
    __builtin_amdgcn_s_barrier();
    PCOMP(14);
    __builtin_amdgcn_s_barrier();
    asm volatile("s_waitcnt vmcnt(0)" ::: "memory");
    __builtin_amdgcn_sched_barrier(0);
    __builtin_amdgcn_s_barrier();
    PCOMP(15);
    __syncthreads();
#undef PSTAGE
#undef PCOMP

    // epilogue: bias (+ scale for qp) + f16, stage in recycled LDS [64][68]
    f16* lds = (f16*)smem;
#pragma unroll
    for (int cf = 0; cf < 4; ++cf) {
        float b = bias[cf * 16 + l15];
#pragma unroll
        for (int r = 0; r < 4; ++r) {
            int rr = wrow + g * 4 + r;            // C layout: row=(l>>4)*4+r
            lds[rr * 68 + cf * 16 + l15] = (f16)((acc[cf][r] + b) * osc);
        }
    }
    __syncthreads();

    if (tens < 2) {
        f16* o = ((tens == 0) ? qp : kp) + (size_t)row0 * 64;
        for (int c = threadIdx.x; c < 64 * 16; c += 256) {   // 8B chunks
            int r = c >> 4, ch = c & 15;
            *(f16x4*)(o + r * 64 + ch * 4) = *(const f16x4*)(&lds[r * 68 + ch * 4]);
        }
    } else {
        int b = row0 >> 12, n0 = row0 & 4095;
        f16* o = vpT + (size_t)b * 64 * 4096 + n0;
        for (int c = threadIdx.x; c < 64 * 16; c += 256) {   // 64 d x 16 chunks of 4 n
            int d = c >> 4, nch = c & 15;
            f16x4 v;
#pragma unroll
            for (int j = 0; j < 4; ++j) v[j] = lds[(nch * 4 + j) * 68 + d];
            *(f16x4*)(o + (size_t)d * 4096 + nch * 4) = v;
        }
    }
}

// ---------------------------------------------------------------------------
// Kernel 2: fused flash attention. Same validated inner loop as R13, but
// grid DOUBLED to 512 (2 blocks/CU, 4 waves/SIMD) by halving per-qg q-rows:
// batch = id&7 (XCD-pinned), qtile = id>>3 (64 q-rows per block).
// block 512 = 8 waves = 2 qg (32 q each) x 4 keysplit s (32 iters of 32 keys).
// LDS-staged K/V via global_load_lds, double-buffered, counted vmcnt,
// raw s_barrier (no drain). Fixed-max softmax, all-register P.
// ---------------------------------------------------------------------------
__global__ __launch_bounds__(512, 2) void ah_attn(
    const f16* __restrict__ qp, const f16* __restrict__ kp, const f16* __restrict__ vpT,
    const int* __restrict__ maskp, float* __restrict__ out) {

    const int id = blockIdx.x;
    const int batch = id & 7, qtile = id >> 3;       // qtile 0..63
    const int lane = threadIdx.x & 63, wave = threadIdx.x >> 6;
    const int l31 = lane & 31, hi2 = lane >> 5;
    const int s = wave & 3, qg = wave >> 2;
    const int q0 = qtile * 64 + qg * 32;
    const float mthr = L2E * (float)maskp[0];

    const f16* qpb = qp + (size_t)batch * 4096 * 64;
    const f16* kpb = kp + (size_t)batch * 4096 * 64;
    const f16* vpb = vpT + (size_t)batch * 64 * 4096;

    __shared__ __align__(16) char smem[65536];
    __shared__ float mlx[2][4][32];

    const int krow = lane >> 3;                    // 0..7
    const int vrow = lane >> 2;                    // 0..15
    const int eswzK = (lane & 7) ^ krow;           // source col16 swizzle (K)
    const int eswzV = (lane & 3) ^ (vrow & 3);     // source col16 swizzle (V)
    const int swzK = l31 & 7, swzV = l31 & 3;      // read-side XOR

#define STAGE(DB, IT) do {                                                          \
    const int _k0 = (((IT) * 4 + s) << 5);                                          \
    char* _b = smem + ((s * 2 + (DB)) * 8192) + (qg ? 4096 : 0);                    \
    if (qg == 0) {                                                                  \
        _Pragma("unroll")                                                           \
        for (int _j = 0; _j < 4; ++_j)                                              \
            gload16(kpb + (size_t)(_k0 + _j * 8 + krow) * 64 + eswzK * 8,           \
                    _b + _j * 1024);                                                \
    } else {                                                                        \
        _Pragma("unroll")                                                           \
        for (int _j = 0; _j < 4; ++_j)                                              \
            gload16(vpb + (size_t)(_j * 16 + vrow) * 4096 + _k0 + eswzV * 8,        \
                    _b + _j * 1024);                                                \
    }                                                                               \
} while (0)

    // hoist Q fragments: B-frag col q = q0 + l31, k = st*16 + hi*8 + j
    f16x8 qf_[4];
#pragma unroll
    for (int st = 0; st < 4; ++st)
        qf_[st] = *(const f16x8*)(qpb + (size_t)(q0 + l31) * 64 + st * 16 + hi2 * 8);

    f32x16 oacc[2];
#pragma unroll
    for (int dt = 0; dt < 2; ++dt)
#pragma unroll
        for (int r = 0; r < 16; ++r) oacc[dt][r] = 0.f;
    float ps = 0.f;

    STAGE(0, 0);
    int db = 0;
    for (int it = 0; it < 32; ++it) {
        if (it < 31) {
            STAGE(db ^ 1, it + 1);
            asm volatile("s_waitcnt vmcnt(4)" ::: "memory");
        } else {
            asm volatile("s_waitcnt vmcnt(0)" ::: "memory");
        }
        __builtin_amdgcn_s_barrier();
        __builtin_amdgcn_sched_barrier(0);

        const char* kb = smem + (s * 2 + db) * 8192;
        const char* vb = kb + 4096;

        // ---- K frags + QK^T ----
        f16x8 ka[4];
#pragma unroll
        for (int st = 0; st < 4; ++st)
            ka[st] = *(const f16x8*)(kb + l31 * 128 + (((st * 2 + hi2) ^ swzK) << 4));
        f32x16 sacc;
#pragma unroll
        for (int r = 0; r < 16; ++r) sacc[r] = 0.f;
#pragma unroll
        for (int st = 0; st < 4; ++st)
            sacc = mfma32(ka[st], qf_[st], sacc);

        // ---- V frags (swap23 gather absorbed in column selection) ----
        f16x8 av[2][2];
#pragma unroll
        for (int dt = 0; dt < 2; ++dt)
#pragma unroll
            for (int t = 0; t < 2; ++t) {
                const char* p = vb + (dt * 32 + l31) * 64 + hi2 * 8;
                *(f16x4*)(&av[dt][t])       = *(const f16x4*)(p + (((t * 2 + 0) ^ swzV) << 4));
                *((f16x4*)(&av[dt][t]) + 1) = *(const f16x4*)(p + (((t * 2 + 1) ^ swzV) << 4));
            }

        // ---- fixed-max softmax: p = exp2(sacc), pack pairs -> PV B-frags ----
        f16x8 pb_[2];
#pragma unroll
        for (int t = 0; t < 2; ++t)
#pragma unroll
            for (int w = 0; w < 4; ++w) {
                float s0 = sacc[t * 8 + 2 * w];
                float s1 = sacc[t * 8 + 2 * w + 1];
                float e0 = __builtin_amdgcn_exp2f(s0);
                float e1 = __builtin_amdgcn_exp2f(s1);
                float p0 = (s0 == mthr) ? 0.f : e0;
                float p1 = (s1 == mthr) ? 0.f : e1;
                ps += p0 + p1;
                ((f16x2*)(&pb_[t]))[w] = cvt_pk(p0, p1);
            }

        // ---- PV ----
#pragma unroll
        for (int dt = 0; dt < 2; ++dt)
#pragma unroll
            for (int t = 0; t < 2; ++t)
                oacc[dt] = mfma32(av[dt][t], pb_[t], oacc[dt]);

        __builtin_amdgcn_sched_barrier(0);
        __builtin_amdgcn_s_barrier();
        __builtin_amdgcn_sched_barrier(0);
        db ^= 1;
    }
#undef STAGE

    // ---- epilogue: Sum(p) exchange + 4-way tree combine in recycled LDS ----
    ps += __shfl_xor(ps, 32);
    if (lane < 32) mlx[qg][s][lane] = ps;
    __syncthreads();

    float Lq = mlx[qg][0][l31] + mlx[qg][1][l31] + mlx[qg][2][l31] + mlx[qg][3][l31];

    float* SC = (float*)smem;        // [qg*2+b][32 regs][64 lanes] = 32KB
#define SCI(B, DT, R) ((((qg * 2 + (B)) * 32) + (DT) * 16 + (R)) * 64 + lane)
    if (s >= 2) {
#pragma unroll
        for (int dt = 0; dt < 2; ++dt)
#pragma unroll
            for (int r = 0; r < 16; ++r)
                SC[SCI(s - 2, dt, r)] = oacc[dt][r];
    }
    __syncthreads();
    if (s < 2) {
#pragma unroll
        for (int dt = 0; dt < 2; ++dt)
#pragma unroll
            for (int r = 0; r < 16; ++r)
                oacc[dt][r] += SC[SCI(s, dt, r)];
        if (s == 1) {
#pragma unroll
            for (int dt = 0; dt < 2; ++dt)
#pragma unroll
                for (int r = 0; r < 16; ++r)
                    SC[SCI(1, dt, r)] = oacc[dt][r];
        }
    }
    __syncthreads();
    if (s == 0) {
        float inv = 1.0f / Lq;
        float* o0 = out + ((size_t)batch * 4096 + q0 + l31) * 64;
#pragma unroll
        for (int dt = 0; dt < 2; ++dt)
#pragma unroll
            for (int rg = 0; rg < 4; ++rg) {  // reg r=rg*4+j -> d = dt*32+rg*8+hi*4+j
                float4 v;
                v.x = (oacc[dt][rg * 4 + 0] + SC[SCI(1, dt, rg * 4 + 0)]) * inv;
                v.y = (oacc[dt][rg * 4 + 1] + SC[SCI(1, dt, rg * 4 + 1)]) * inv;
                v.z = (oacc[dt][rg * 4 + 2] + SC[SCI(1, dt, rg * 4 + 2)]) * inv;
                v.w = (oacc[dt][rg * 4 + 3] + SC[SCI(1, dt, rg * 4 + 3)]) * inv;
                *(float4*)(o0 + dt * 32 + rg * 8 + hi2 * 4) = v;
            }
    }
#undef SCI
}

// ---------------------------------------------------------------------------
extern "C" void kernel_launch(void* const* d_in, const int* in_sizes, int n_in,
                              void* d_out, int out_size, void* d_ws, size_t ws_size,
                              hipStream_t stream) {
    const float* q  = (const float*)d_in[0];
    const float* k  = (const float*)d_in[1];
    const float* v  = (const float*)d_in[2];
    const float* Wq = (const float*)d_in[3];
    const float* bq = (const float*)d_in[4];
    const float* Wk = (const float*)d_in[5];
    const float* bk = (const float*)d_in[6];
    const float* Wv = (const float*)d_in[7];
    const float* bv = (const float*)d_in[8];
    const int* mask = (const int*)d_in[9];
    float* out = (float*)d_out;

    const size_t NTOK = (size_t)8 * 4096;      // 32768 rows
    f16* qp  = (f16*)d_ws;                     // [8][4096][64]  (pre-scaled by QSC)
    f16* kp  = qp + NTOK * 64;                 // [8][4096][64]
    f16* vpT = kp + NTOK * 64;                 // [8][64][4096]
    f16* WT  = vpT + NTOK * 64;                // [3][64][512]

    ah_wt_prep<<<dim3(3), 256, 0, stream>>>(Wq, Wk, Wv, WT);
    ah_proj<<<dim3(512, 3), 256, 0, stream>>>(q, k, v, bq, bk, bv, WT, qp, kp, vpT);
    ah_attn<<<dim3(512), 512, 0, stream>>>(qp, kp, vpT, mask, out);
}

// Round 17
// 119.177 us; speedup vs baseline: 1.2210x; 1.2210x over previous
//
#include <hip/hip_runtime.h>

typedef _Float16 f16;
typedef _Float16 f16x2 __attribute__((ext_vector_type(2)));
typedef _Float16 f16x4 __attribute__((ext_vector_type(4)));
typedef _Float16 f16x8 __attribute__((ext_vector_type(8)));
typedef __fp16   h16x2 __attribute__((ext_vector_type(2)));
typedef float    f32x4 __attribute__((ext_vector_type(4)));
typedef float    f32x16 __attribute__((ext_vector_type(16)));

static constexpr float L2E = 1.44269504088896340736f;
// folded into q-projection: (1/sqrt(64)) * log2(e)
static constexpr float QSC = 0.18033688011112042f;

static __device__ __forceinline__ f32x4 mfma16(f16x8 a, f16x8 b, f32x4 c) {
    return __builtin_amdgcn_mfma_f32_16x16x32_f16(a, b, c, 0, 0, 0);
}
static __device__ __forceinline__ f32x16 mfma32(f16x8 a, f16x8 b, f32x16 c) {
    return __builtin_amdgcn_mfma_f32_32x32x16_f16(a, b, c, 0, 0, 0);
}
static __device__ __forceinline__ f16x2 cvt_pk(float a, float b) {
    h16x2 t = __builtin_amdgcn_cvt_pkrtz(a, b);
    return __builtin_bit_cast(f16x2, t);
}
// async global->LDS DMA, 16B per lane. LDS dest = WAVE-UNIFORM base + lane*16.
static __device__ __forceinline__ void gload16(const void* g, void* l) {
    __builtin_amdgcn_global_load_lds(
        (const __attribute__((address_space(1))) unsigned int*)g,
        (__attribute__((address_space(3))) unsigned int*)l, 16, 0, 0);
}

// ---------------------------------------------------------------------------
// Kernel 0: transpose W [512][64] f32 -> WT [64][512] f16 (per tensor)
// ---------------------------------------------------------------------------
__global__ void ah_wt_prep(const float* __restrict__ Wq,
                           const float* __restrict__ Wk,
                           const float* __restrict__ Wv,
                           f16* __restrict__ WT) {
    const float* W = (blockIdx.x == 0) ? Wq : (blockIdx.x == 1) ? Wk : Wv;
    f16* o = WT + (size_t)blockIdx.x * (64 * 512);
    for (int i = threadIdx.x; i < 64 * 512; i += blockDim.x) {
        int col = i >> 9, e = i & 511;
        o[i] = (f16)W[e * 64 + col];
    }
}

// ---------------------------------------------------------------------------
// Kernel 1: projection  P = X @ W + b  (X fp32 [32768][512] -> out f16).
// R13 verbatim (best measured): DMA barrier-pipeline, DEPTH-3, BK=32,
// 4 buffers x (X 8KB + W 4KB) = 48KB LDS -> 3 blocks/CU. vmcnt(9) steady,
// drain 6/3/0. X XOR-swizzled (unit^=row&7, source-pre-swizzled); W linear.
// grid (512 row-tiles of 64, 3 tensors), block 256 = 4 waves x 16 rows.
// tensor 0 -> qp (scaled QSC), 1 -> kp, 2 -> vpT [b][64][4096]
// ---------------------------------------------------------------------------
__global__ __launch_bounds__(256, 3) void ah_proj(
    const float* __restrict__ Xq, const float* __restrict__ Xk, const float* __restrict__ Xv,
    const float* __restrict__ bq, const float* __restrict__ bk, const float* __restrict__ bv,
    const f16* __restrict__ WT,
    f16* __restrict__ qp, f16* __restrict__ kp, f16* __restrict__ vpT) {

    const int tens = blockIdx.y;
    const float* X    = (tens == 0) ? Xq : (tens == 1) ? Xk : Xv;
    const float* bias = (tens == 0) ? bq : (tens == 1) ? bk : bv;
    const f16* wt = WT + (size_t)tens * (64 * 512);
    const float osc = (tens == 0) ? QSC : 1.0f;

    const int lane = threadIdx.x & 63;
    const int wave = threadIdx.x >> 6;
    const int l15 = lane & 15, g = lane >> 4;
    const int row0 = blockIdx.x * 64;
    const int wrow = wave * 16;

    __shared__ __align__(16) char smem[49152];   // 4 x (X 8KB | W 4KB)

    const int xr8 = lane >> 3;                   // 0..7
    const int xsu = (lane & 7) ^ xr8;            // source unit (pre-swizzled)

#define PSTAGE(KC) do {                                                              \
    char* _xb = smem + ((KC) & 3) * 12288;                                           \
    char* _wb = _xb + 8192;                                                          \
    gload16(X + (size_t)(row0 + wrow + xr8) * 512 + (KC) * 32 + xsu * 4,             \
            _xb + wave * 2048);                                                      \
    gload16(X + (size_t)(row0 + wrow + 8 + xr8) * 512 + (KC) * 32 + xsu * 4,         \
            _xb + wave * 2048 + 1024);                                               \
    gload16(wt + (size_t)(wrow + (lane >> 2)) * 512 + (KC) * 32 + (lane & 3) * 8,    \
            _wb + wave * 1024);                                                      \
} while (0)

    f32x4 acc[4];
#pragma unroll
    for (int b = 0; b < 4; ++b) acc[b] = (f32x4){0.f, 0.f, 0.f, 0.f};

#define PCOMP(KC) do {                                                               \
    const char* _xb = smem + ((KC) & 3) * 12288;                                     \
    const char* _wb = _xb + 8192;                                                    \
    const char* _cb = _xb + (wrow + l15) * 128;                                      \
    float4 v0 = *(const float4*)(_cb + (((2 * g + 0) ^ (l15 & 7)) << 4));            \
    float4 v1 = *(const float4*)(_cb + (((2 * g + 1) ^ (l15 & 7)) << 4));            \
    f16x2 p0 = cvt_pk(v0.x, v0.y), p1 = cvt_pk(v0.z, v0.w);                          \
    f16x2 p2 = cvt_pk(v1.x, v1.y), p3 = cvt_pk(v1.z, v1.w);                          \
    f16x8 a;                                                                         \
    a[0] = p0[0]; a[1] = p0[1]; a[2] = p1[0]; a[3] = p1[1];                          \
    a[4] = p2[0]; a[5] = p2[1]; a[6] = p3[0]; a[7] = p3[1];                          \
    _Pragma("unroll")                                                                \
    for (int cf = 0; cf < 4; ++cf) {                                                 \
        f16x8 bfr = *(const f16x8*)(_wb + (cf * 16 + l15) * 64 + g * 16);            \
        acc[cf] = mfma16(a, bfr, acc[cf]);                                           \
    }                                                                                \
} while (0)

    PSTAGE(0); PSTAGE(1); PSTAGE(2);
    for (int kc = 0; kc < 13; ++kc) {            // steady state: depth-3
        PSTAGE(kc + 3);
        asm volatile("s_waitcnt vmcnt(9)" ::: "memory");
        __builtin_amdgcn_sched_barrier(0);
        __builtin_amdgcn_s_barrier();
        __builtin_amdgcn_sched_barrier(0);
        PCOMP(kc);
        __builtin_amdgcn_sched_barrier(0);
        __builtin_amdgcn_s_barrier();
    }
    // drain: chunks 13,14,15
    asm volatile("s_waitcnt vmcnt(6)" ::: "memory");
    __builtin_amdgcn_sched_barrier(0);
    __builtin_amdgcn_s_barrier();
    PCOMP(13);
    __builtin_amdgcn_s_barrier();
    asm volatile("s_waitcnt vmcnt(3)" ::: "memory");
    __builtin_amdgcn_sched_barrier(0);
    __builtin_amdgcn_s_barrier();
    PCOMP(14);
    __builtin_amdgcn_s_barrier();
    asm volatile("s_waitcnt vmcnt(0)" ::: "memory");
    __builtin_amdgcn_sched_barrier(0);
    __builtin_amdgcn_s_barrier();
    PCOMP(15);
    __syncthreads();
#undef PSTAGE
#undef PCOMP

    // epilogue: bias (+ scale for qp) + f16, stage in recycled LDS [64][68]
    f16* lds = (f16*)smem;
#pragma unroll
    for (int cf = 0; cf < 4; ++cf) {
        float b = bias[cf * 16 + l15];
#pragma unroll
        for (int r = 0; r < 4; ++r) {
            int rr = wrow + g * 4 + r;            // C layout: row=(l>>4)*4+r
            lds[rr * 68 + cf * 16 + l15] = (f16)((acc[cf][r] + b) * osc);
        }
    }
    __syncthreads();

    if (tens < 2) {
        f16* o = ((tens == 0) ? qp : kp) + (size_t)row0 * 64;
        for (int c = threadIdx.x; c < 64 * 16; c += 256) {   // 8B chunks
            int r = c >> 4, ch = c & 15;
            *(f16x4*)(o + r * 64 + ch * 4) = *(const f16x4*)(&lds[r * 68 + ch * 4]);
        }
    } else {
        int b = row0 >> 12, n0 = row0 & 4095;
        f16* o = vpT + (size_t)b * 64 * 4096 + n0;
        for (int c = threadIdx.x; c < 64 * 16; c += 256) {   // 64 d x 16 chunks of 4 n
            int d = c >> 4, nch = c & 15;
            f16x4 v;
#pragma unroll
            for (int j = 0; j < 4; ++j) v[j] = lds[(nch * 4 + j) * 68 + d];
            *(f16x4*)(o + (size_t)d * 4096 + nch * 4) = v;
        }
    }
}

// ---------------------------------------------------------------------------
// Kernel 2: fused flash attention (R13 structure; V-tile layout fixed).
// grid 256: batch = id&7 (XCD-pinned), qtile = id>>3 (128 q-rows).
// block 512 = 8 waves = 2 qg (64 q) x 4 keysplit s (1024 keys, 32 iters of 32).
// LDS-staged K/V via global_load_lds, double-buffered, counted vmcnt, raw
// s_barrier. V tile now UNIT-MAJOR per 1KB chunk: lane l -> (d=l&15, u=l>>4),
// addr(d,u) = (d>>4)*1024 + u*256 + (d&15)*16 -> read bank = (d&7)*4+hi2*2:
// 16 bank-pairs x 4 lanes = b64 minimum phases (was 8 lanes/pair = 2x).
// No V source swizzle needed. K path unchanged (verified optimal).
// ---------------------------------------------------------------------------
__global__ __launch_bounds__(512, 2) void ah_attn(
    const f16* __restrict__ qp, const f16* __restrict__ kp, const f16* __restrict__ vpT,
    const int* __restrict__ maskp, float* __restrict__ out) {

    const int id = blockIdx.x;
    const int batch = id & 7, qtile = id >> 3;
    const int lane = threadIdx.x & 63, wave = threadIdx.x >> 6;
    const int l31 = lane & 31, hi2 = lane >> 5;
    const int s = wave & 3, qg = wave >> 2;
    const int q0 = qtile * 128 + qg * 64;
    const float mthr = L2E * (float)maskp[0];

    const f16* qpb = qp + (size_t)batch * 4096 * 64;
    const f16* kpb = kp + (size_t)batch * 4096 * 64;
    const f16* vpb = vpT + (size_t)batch * 64 * 4096;

    __shared__ __align__(16) char smem[65536];
    __shared__ float mlx[2][4][2][32];

    const int krow = lane >> 3;                    // 0..7
    const int eswzK = (lane & 7) ^ krow;           // source col16 swizzle (K)
    const int swzK = l31 & 7;                      // read-side XOR (K)

#define STAGE(DB, IT) do {                                                          \
    const int _k0 = (((IT) * 4 + s) << 5);                                          \
    char* _b = smem + ((s * 2 + (DB)) * 8192) + (qg ? 4096 : 0);                    \
    if (qg == 0) {                                                                  \
        _Pragma("unroll")                                                           \
        for (int _j = 0; _j < 4; ++_j)                                              \
            gload16(kpb + (size_t)(_k0 + _j * 8 + krow) * 64 + eswzK * 8,           \
                    _b + _j * 1024);                                                \
    } else {                                                                        \
        _Pragma("unroll")                                                           \
        for (int _j = 0; _j < 4; ++_j)                                              \
            gload16(vpb + (size_t)(_j * 16 + (lane & 15)) * 4096 + _k0 +            \
                        (lane >> 4) * 8,                                            \
                    _b + _j * 1024);                                                \
    }                                                                               \
} while (0)

    f16x8 qf_[2][4];
#pragma unroll
    for (int qt = 0; qt < 2; ++qt)
#pragma unroll
        for (int st = 0; st < 4; ++st)
            qf_[qt][st] = *(const f16x8*)(qpb + (size_t)(q0 + qt * 32 + l31) * 64 + st * 16 + hi2 * 8);

    f32x16 oacc[2][2];
#pragma unroll
    for (int dt = 0; dt < 2; ++dt)
#pragma unroll
        for (int qt = 0; qt < 2; ++qt)
#pragma unroll
            for (int r = 0; r < 16; ++r) oacc[dt][qt][r] = 0.f;
    float ps[2] = {0.f, 0.f};

    STAGE(0, 0);
    int db = 0;
    for (int it = 0; it < 32; ++it) {
        if (it < 31) {
            STAGE(db ^ 1, it + 1);
            asm volatile("s_waitcnt vmcnt(4)" ::: "memory");
        } else {
            asm volatile("s_waitcnt vmcnt(0)" ::: "memory");
        }
        __builtin_amdgcn_s_barrier();
        __builtin_amdgcn_sched_barrier(0);

        const char* kb = smem + (s * 2 + db) * 8192;
        const char* vb = kb + 4096;

        // ---- K frags + QK^T ----
        f16x8 ka[4];
#pragma unroll
        for (int st = 0; st < 4; ++st)
            ka[st] = *(const f16x8*)(kb + l31 * 128 + (((st * 2 + hi2) ^ swzK) << 4));
        f32x16 sacc[2];
#pragma unroll
        for (int qt = 0; qt < 2; ++qt)
#pragma unroll
            for (int r = 0; r < 16; ++r) sacc[qt][r] = 0.f;
#pragma unroll
        for (int st = 0; st < 4; ++st)
#pragma unroll
            for (int qt = 0; qt < 2; ++qt)
                sacc[qt] = mfma32(ka[st], qf_[qt][st], sacc[qt]);

        // ---- V frags (unit-major layout; swap23 gather in unit selection) ----
        f16x8 av[2][2];
#pragma unroll
        for (int dt = 0; dt < 2; ++dt) {
            const char* vchunk = vb + (dt * 2 + (l31 >> 4)) * 1024 + (l31 & 15) * 16 + hi2 * 8;
#pragma unroll
            for (int t = 0; t < 2; ++t) {
                *(f16x4*)(&av[dt][t])       = *(const f16x4*)(vchunk + (t * 2 + 0) * 256);
                *((f16x4*)(&av[dt][t]) + 1) = *(const f16x4*)(vchunk + (t * 2 + 1) * 256);
            }
        }

        // ---- fixed-max softmax: p = exp2(sacc), pack pairs -> PV B-frags ----
        f16x8 pb_[2][2];
#pragma unroll
        for (int qt = 0; qt < 2; ++qt)
#pragma unroll
            for (int t = 0; t < 2; ++t)
#pragma unroll
                for (int w = 0; w < 4; ++w) {
                    float s0 = sacc[qt][t * 8 + 2 * w];
                    float s1 = sacc[qt][t * 8 + 2 * w + 1];
                    float e0 = __builtin_amdgcn_exp2f(s0);
                    float e1 = __builtin_amdgcn_exp2f(s1);
                    float p0 = (s0 == mthr) ? 0.f : e0;
                    float p1 = (s1 == mthr) ? 0.f : e1;
                    ps[qt] += p0 + p1;
                    ((f16x2*)(&pb_[qt][t]))[w] = cvt_pk(p0, p1);
                }

        // ---- PV ----
#pragma unroll
        for (int dt = 0; dt < 2; ++dt)
#pragma unroll
            for (int qt = 0; qt < 2; ++qt)
#pragma unroll
                for (int t = 0; t < 2; ++t)
                    oacc[dt][qt] = mfma32(av[dt][t], pb_[qt][t], oacc[dt][qt]);

        __builtin_amdgcn_sched_barrier(0);
        __builtin_amdgcn_s_barrier();
        __builtin_amdgcn_sched_barrier(0);
        db ^= 1;
    }
#undef STAGE

    // ---- epilogue: Sum(p) exchange + 4-way tree combine in recycled LDS ----
    ps[0] += __shfl_xor(ps[0], 32);
    ps[1] += __shfl_xor(ps[1], 32);
    if (lane < 32) { mlx[qg][s][0][lane] = ps[0]; mlx[qg][s][1][lane] = ps[1]; }
    __syncthreads();

    float* SC = (float*)smem;        // [qg*2+b][64 regs][64 lanes]
#define SCI(B, DT, QT, R) ((((qg * 2 + (B)) * 64) + ((DT) * 2 + (QT)) * 16 + (R)) * 64 + lane)
    if (s >= 2) {
#pragma unroll
        for (int dt = 0; dt < 2; ++dt)
#pragma unroll
            for (int qt = 0; qt < 2; ++qt)
#pragma unroll
                for (int r = 0; r < 16; ++r)
                    SC[SCI(s - 2, dt, qt, r)] = oacc[dt][qt][r];
    }
    __syncthreads();
    if (s < 2) {
#pragma unroll
        for (int dt = 0; dt < 2; ++dt)
#pragma unroll
            for (int qt = 0; qt < 2; ++qt)
#pragma unroll
                for (int r = 0; r < 16; ++r)
                    oacc[dt][qt][r] += SC[SCI(s, dt, qt, r)];
        if (s == 1) {
#pragma unroll
            for (int dt = 0; dt < 2; ++dt)
#pragma unroll
                for (int qt = 0; qt < 2; ++qt)
#pragma unroll
                    for (int r = 0; r < 16; ++r)
                        SC[SCI(1, dt, qt, r)] = oacc[dt][qt][r];
        }
    }
    __syncthreads();
    if (s == 0) {
        float inv[2];
#pragma unroll
        for (int qt = 0; qt < 2; ++qt)
            inv[qt] = 1.0f / (mlx[qg][0][qt][l31] + mlx[qg][1][qt][l31] +
                              mlx[qg][2][qt][l31] + mlx[qg][3][qt][l31]);
#pragma unroll
        for (int qt = 0; qt < 2; ++qt) {
            float* o0 = out + ((size_t)batch * 4096 + q0 + qt * 32 + l31) * 64;
#pragma unroll
            for (int dt = 0; dt < 2; ++dt)
#pragma unroll
                for (int rg = 0; rg < 4; ++rg) {  // reg r=rg*4+j -> d = dt*32+rg*8+hi*4+j
                    float4 v;
                    v.x = (oacc[dt][qt][rg * 4 + 0] + SC[SCI(1, dt, qt, rg * 4 + 0)]) * inv[qt];
                    v.y = (oacc[dt][qt][rg * 4 + 1] + SC[SCI(1, dt, qt, rg * 4 + 1)]) * inv[qt];
                    v.z = (oacc[dt][qt][rg * 4 + 2] + SC[SCI(1, dt, qt, rg * 4 + 2)]) * inv[qt];
                    v.w = (oacc[dt][qt][rg * 4 + 3] + SC[SCI(1, dt, qt, rg * 4 + 3)]) * inv[qt];
                    *(float4*)(o0 + dt * 32 + rg * 8 + hi2 * 4) = v;
                }
        }
    }
#undef SCI
}

// ---------------------------------------------------------------------------
extern "C" void kernel_launch(void* const* d_in, const int* in_sizes, int n_in,
                              void* d_out, int out_size, void* d_ws, size_t ws_size,
                              hipStream_t stream) {
    const float* q  = (const float*)d_in[0];
    const float* k  = (const float*)d_in[1];
    const float* v  = (const float*)d_in[2];
    const float* Wq = (const float*)d_in[3];
    const float* bq = (const float*)d_in[4];
    const float* Wk = (const float*)d_in[5];
    const float* bk = (const float*)d_in[6];
    const float* Wv = (const float*)d_in[7];
    const float* bv = (const float*)d_in[8];
    const int* mask = (const int*)d_in[9];
    float* out = (float*)d_out;

    const size_t NTOK = (size_t)8 * 4096;      // 32768 rows
    f16* qp  = (f16*)d_ws;                     // [8][4096][64]  (pre-scaled by QSC)
    f16* kp  = qp + NTOK * 64;                 // [8][4096][64]
    f16* vpT = kp + NTOK * 64;                 // [8][64][4096]
    f16* WT  = vpT + NTOK * 64;                // [3][64][512]

    ah_wt_prep<<<dim3(3), 256, 0, stream>>>(Wq, Wk, Wv, WT);
    ah_proj<<<dim3(512, 3), 256, 0, stream>>>(q, k, v, bq, bk, bv, WT, qp, kp, vpT);
    ah_attn<<<dim3(256), 512, 0, stream>>>(qp, kp, vpT, mask, out);
}

// Round 18
// 115.481 us; speedup vs baseline: 1.2601x; 1.0320x over previous
//
#include <hip/hip_runtime.h>

typedef _Float16 f16;
typedef _Float16 f16x2 __attribute__((ext_vector_type(2)));
typedef _Float16 f16x4 __attribute__((ext_vector_type(4)));
typedef _Float16 f16x8 __attribute__((ext_vector_type(8)));
typedef __fp16   h16x2 __attribute__((ext_vector_type(2)));
typedef float    f32x4 __attribute__((ext_vector_type(4)));
typedef float    f32x16 __attribute__((ext_vector_type(16)));

static constexpr float L2E = 1.44269504088896340736f;
// folded into q-projection: (1/sqrt(64)) * log2(e)
static constexpr float QSC = 0.18033688011112042f;

static __device__ __forceinline__ f32x4 mfma16(f16x8 a, f16x8 b, f32x4 c) {
    return __builtin_amdgcn_mfma_f32_16x16x32_f16(a, b, c, 0, 0, 0);
}
static __device__ __forceinline__ f32x16 mfma32(f16x8 a, f16x8 b, f32x16 c) {
    return __builtin_amdgcn_mfma_f32_32x32x16_f16(a, b, c, 0, 0, 0);
}
static __device__ __forceinline__ f16x2 cvt_pk(float a, float b) {
    h16x2 t = __builtin_amdgcn_cvt_pkrtz(a, b);
    return __builtin_bit_cast(f16x2, t);
}
// async global->LDS DMA, 16B per lane. LDS dest = WAVE-UNIFORM base + lane*16.
static __device__ __forceinline__ void gload16(const void* g, void* l) {
    __builtin_amdgcn_global_load_lds(
        (const __attribute__((address_space(1))) unsigned int*)g,
        (__attribute__((address_space(3))) unsigned int*)l, 16, 0, 0);
}

// ---------------------------------------------------------------------------
// Kernel 0: transpose W [512][64] f32 -> WT [64][512] f16 (per tensor)
// ---------------------------------------------------------------------------
__global__ void ah_wt_prep(const float* __restrict__ Wq,
                           const float* __restrict__ Wk,
                           const float* __restrict__ Wv,
                           f16* __restrict__ WT) {
    const float* W = (blockIdx.x == 0) ? Wq : (blockIdx.x == 1) ? Wk : Wv;
    f16* o = WT + (size_t)blockIdx.x * (64 * 512);
    for (int i = threadIdx.x; i < 64 * 512; i += blockDim.x) {
        int col = i >> 9, e = i & 511;
        o[i] = (f16)W[e * 64 + col];
    }
}

// ---------------------------------------------------------------------------
// Kernel 1: projection  P = X @ W + b  (X fp32 [32768][512] -> out f16).
// R13 verbatim (best measured): DMA barrier-pipeline, DEPTH-3, BK=32,
// 4 buffers x (X 8KB + W 4KB) = 48KB LDS -> 3 blocks/CU. vmcnt(9) steady,
// drain 6/3/0. X XOR-swizzled (unit^=row&7, source-pre-swizzled); W linear.
// grid (512 row-tiles of 64, 3 tensors), block 256 = 4 waves x 16 rows.
// tensor 0 -> qp (scaled QSC), 1 -> kp, 2 -> vpT [b][64][4096]
// ---------------------------------------------------------------------------
__global__ __launch_bounds__(256, 3) void ah_proj(
    const float* __restrict__ Xq, const float* __restrict__ Xk, const float* __restrict__ Xv,
    const float* __restrict__ bq, const float* __restrict__ bk, const float* __restrict__ bv,
    const f16* __restrict__ WT,
    f16* __restrict__ qp, f16* __restrict__ kp, f16* __restrict__ vpT) {

    const int tens = blockIdx.y;
    const float* X    = (tens == 0) ? Xq : (tens == 1) ? Xk : Xv;
    const float* bias = (tens == 0) ? bq : (tens == 1) ? bk : bv;
    const f16* wt = WT + (size_t)tens * (64 * 512);
    const float osc = (tens == 0) ? QSC : 1.0f;

    const int lane = threadIdx.x & 63;
    const int wave = threadIdx.x >> 6;
    const int l15 = lane & 15, g = lane >> 4;
    const int row0 = blockIdx.x * 64;
    const int wrow = wave * 16;

    __shared__ __align__(16) char smem[49152];   // 4 x (X 8KB | W 4KB)

    const int xr8 = lane >> 3;                   // 0..7
    const int xsu = (lane & 7) ^ xr8;            // source unit (pre-swizzled)

#define PSTAGE(KC) do {                                                              \
    char* _xb = smem + ((KC) & 3) * 12288;                                           \
    char* _wb = _xb + 8192;                                                          \
    gload16(X + (size_t)(row0 + wrow + xr8) * 512 + (KC) * 32 + xsu * 4,             \
            _xb + wave * 2048);                                                      \
    gload16(X + (size_t)(row0 + wrow + 8 + xr8) * 512 + (KC) * 32 + xsu * 4,         \
            _xb + wave * 2048 + 1024);                                               \
    gload16(wt + (size_t)(wrow + (lane >> 2)) * 512 + (KC) * 32 + (lane & 3) * 8,    \
            _wb + wave * 1024);                                                      \
} while (0)

    f32x4 acc[4];
#pragma unroll
    for (int b = 0; b < 4; ++b) acc[b] = (f32x4){0.f, 0.f, 0.f, 0.f};

#define PCOMP(KC) do {                                                               \
    const char* _xb = smem + ((KC) & 3) * 12288;                                     \
    const char* _wb = _xb + 8192;                                                    \
    const char* _cb = _xb + (wrow + l15) * 128;                                      \
    float4 v0 = *(const float4*)(_cb + (((2 * g + 0) ^ (l15 & 7)) << 4));            \
    float4 v1 = *(const float4*)(_cb + (((2 * g + 1) ^ (l15 & 7)) << 4));            \
    f16x2 p0 = cvt_pk(v0.x, v0.y), p1 = cvt_pk(v0.z, v0.w);                          \
    f16x2 p2 = cvt_pk(v1.x, v1.y), p3 = cvt_pk(v1.z, v1.w);                          \
    f16x8 a;                                                                         \
    a[0] = p0[0]; a[1] = p0[1]; a[2] = p1[0]; a[3] = p1[1];                          \
    a[4] = p2[0]; a[5] = p2[1]; a[6] = p3[0]; a[7] = p3[1];                          \
    _Pragma("unroll")                                                                \
    for (int cf = 0; cf < 4; ++cf) {                                                 \
        f16x8 bfr = *(const f16x8*)(_wb + (cf * 16 + l15) * 64 + g * 16);            \
        acc[cf] = mfma16(a, bfr, acc[cf]);                                           \
    }                                                                                \
} while (0)

    PSTAGE(0); PSTAGE(1); PSTAGE(2);
    for (int kc = 0; kc < 13; ++kc) {            // steady state: depth-3
        PSTAGE(kc + 3);
        asm volatile("s_waitcnt vmcnt(9)" ::: "memory");
        __builtin_amdgcn_sched_barrier(0);
        __builtin_amdgcn_s_barrier();
        __builtin_amdgcn_sched_barrier(0);
        PCOMP(kc);
        __builtin_amdgcn_sched_barrier(0);
        __builtin_amdgcn_s_barrier();
    }
    // drain: chunks 13,14,15
    asm volatile("s_waitcnt vmcnt(6)" ::: "memory");
    __builtin_amdgcn_sched_barrier(0);
    __builtin_amdgcn_s_barrier();
    PCOMP(13);
    __builtin_amdgcn_s_barrier();
    asm volatile("s_waitcnt vmcnt(3)" ::: "memory");
    __builtin_amdgcn_sched_barrier(0);
    __builtin_amdgcn_s_barrier();
    PCOMP(14);
    __builtin_amdgcn_s_barrier();
    asm volatile("s_waitcnt vmcnt(0)" ::: "memory");
    __builtin_amdgcn_sched_barrier(0);
    __builtin_amdgcn_s_barrier();
    PCOMP(15);
    __syncthreads();
#undef PSTAGE
#undef PCOMP

    // epilogue: bias (+ scale for qp) + f16, stage in recycled LDS [64][68]
    f16* lds = (f16*)smem;
#pragma unroll
    for (int cf = 0; cf < 4; ++cf) {
        float b = bias[cf * 16 + l15];
#pragma unroll
        for (int r = 0; r < 4; ++r) {
            int rr = wrow + g * 4 + r;            // C layout: row=(l>>4)*4+r
            lds[rr * 68 + cf * 16 + l15] = (f16)((acc[cf][r] + b) * osc);
        }
    }
    __syncthreads();

    if (tens < 2) {
        f16* o = ((tens == 0) ? qp : kp) + (size_t)row0 * 64;
        for (int c = threadIdx.x; c < 64 * 16; c += 256) {   // 8B chunks
            int r = c >> 4, ch = c & 15;
            *(f16x4*)(o + r * 64 + ch * 4) = *(const f16x4*)(&lds[r * 68 + ch * 4]);
        }
    } else {
        int b = row0 >> 12, n0 = row0 & 4095;
        f16* o = vpT + (size_t)b * 64 * 4096 + n0;
        for (int c = threadIdx.x; c < 64 * 16; c += 256) {   // 64 d x 16 chunks of 4 n
            int d = c >> 4, nch = c & 15;
            f16x4 v;
#pragma unroll
            for (int j = 0; j < 4; ++j) v[j] = lds[(nch * 4 + j) * 68 + d];
            *(f16x4*)(o + (size_t)d * 4096 + nch * 4) = v;
        }
    }
}

// ---------------------------------------------------------------------------
// Kernel 2: fused flash attention. R17 inner loop, but 4-DEEP staging ring
// with ONE barrier per iteration (was 2): per iter i:
//   vmcnt(8) -> compute(buf i&3) -> s_barrier -> stage(buf (i+3)&3).
// The end-of-iter barrier proves all waves finished reading buf (i-1)&3 ==
// (i+3)&3 before overwrite; each stage has 3 iters of flight before its wait.
// LDS: [4 s][4 buf][K 4KB | V 4KB] = 128KB (grid = 1 block/CU anyway).
// V tile unit-major (R17, conflict-minimal); K XOR-swizzled (validated).
// grid 256: batch = id&7 (XCD-pinned), qtile = id>>3 (128 q-rows).
// block 512 = 8 waves = 2 qg (64 q) x 4 keysplit s (1024 keys, 32 iters of 32).
// ---------------------------------------------------------------------------
__global__ __launch_bounds__(512, 1) void ah_attn(
    const f16* __restrict__ qp, const f16* __restrict__ kp, const f16* __restrict__ vpT,
    const int* __restrict__ maskp, float* __restrict__ out) {

    const int id = blockIdx.x;
    const int batch = id & 7, qtile = id >> 3;
    const int lane = threadIdx.x & 63, wave = threadIdx.x >> 6;
    const int l31 = lane & 31, hi2 = lane >> 5;
    const int s = wave & 3, qg = wave >> 2;
    const int q0 = qtile * 128 + qg * 64;
    const float mthr = L2E * (float)maskp[0];

    const f16* qpb = qp + (size_t)batch * 4096 * 64;
    const f16* kpb = kp + (size_t)batch * 4096 * 64;
    const f16* vpb = vpT + (size_t)batch * 64 * 4096;

    __shared__ __align__(16) char smem[131072];    // [4 s][4 buf][8KB]
    __shared__ float mlx[2][4][2][32];

    const int krow = lane >> 3;                    // 0..7
    const int eswzK = (lane & 7) ^ krow;           // source col16 swizzle (K)
    const int swzK = l31 & 7;                      // read-side XOR (K)

#define STAGE(BUF, IT) do {                                                         \
    const int _k0 = (((IT) * 4 + s) << 5);                                          \
    char* _b = smem + (s * 4 + (BUF)) * 8192 + (qg ? 4096 : 0);                     \
    if (qg == 0) {                                                                  \
        _Pragma("unroll")                                                           \
        for (int _j = 0; _j < 4; ++_j)                                              \
            gload16(kpb + (size_t)(_k0 + _j * 8 + krow) * 64 + eswzK * 8,           \
                    _b + _j * 1024);                                                \
    } else {                                                                        \
        _Pragma("unroll")                                                           \
        for (int _j = 0; _j < 4; ++_j)                                              \
            gload16(vpb + (size_t)(_j * 16 + (lane & 15)) * 4096 + _k0 +            \
                        (lane >> 4) * 8,                                            \
                    _b + _j * 1024);                                                \
    }                                                                               \
} while (0)

    f16x8 qf_[2][4];
#pragma unroll
    for (int qt = 0; qt < 2; ++qt)
#pragma unroll
        for (int st = 0; st < 4; ++st)
            qf_[qt][st] = *(const f16x8*)(qpb + (size_t)(q0 + qt * 32 + l31) * 64 + st * 16 + hi2 * 8);

    f32x16 oacc[2][2];
#pragma unroll
    for (int dt = 0; dt < 2; ++dt)
#pragma unroll
        for (int qt = 0; qt < 2; ++qt)
#pragma unroll
            for (int r = 0; r < 16; ++r) oacc[dt][qt][r] = 0.f;
    float ps[2] = {0.f, 0.f};

    STAGE(0, 0); STAGE(1, 1); STAGE(2, 2);
    __builtin_amdgcn_s_barrier();                 // stages issued before loop
    for (int it = 0; it < 32; ++it) {
        if (it < 30)      asm volatile("s_waitcnt vmcnt(8)" ::: "memory");
        else if (it == 30) asm volatile("s_waitcnt vmcnt(4)" ::: "memory");
        else              asm volatile("s_waitcnt vmcnt(0)" ::: "memory");
        __builtin_amdgcn_sched_barrier(0);

        const char* kb = smem + (s * 4 + (it & 3)) * 8192;
        const char* vb = kb + 4096;

        // ---- K frags + QK^T ----
        f16x8 ka[4];
#pragma unroll
        for (int st = 0; st < 4; ++st)
            ka[st] = *(const f16x8*)(kb + l31 * 128 + (((st * 2 + hi2) ^ swzK) << 4));
        f32x16 sacc[2];
#pragma unroll
        for (int qt = 0; qt < 2; ++qt)
#pragma unroll
            for (int r = 0; r < 16; ++r) sacc[qt][r] = 0.f;
#pragma unroll
        for (int st = 0; st < 4; ++st)
#pragma unroll
            for (int qt = 0; qt < 2; ++qt)
                sacc[qt] = mfma32(ka[st], qf_[qt][st], sacc[qt]);

        // ---- V frags (unit-major layout) ----
        f16x8 av[2][2];
#pragma unroll
        for (int dt = 0; dt < 2; ++dt) {
            const char* vchunk = vb + (dt * 2 + (l31 >> 4)) * 1024 + (l31 & 15) * 16 + hi2 * 8;
#pragma unroll
            for (int t = 0; t < 2; ++t) {
                *(f16x4*)(&av[dt][t])       = *(const f16x4*)(vchunk + (t * 2 + 0) * 256);
                *((f16x4*)(&av[dt][t]) + 1) = *(const f16x4*)(vchunk + (t * 2 + 1) * 256);
            }
        }

        // ---- fixed-max softmax: p = exp2(sacc), pack pairs -> PV B-frags ----
        f16x8 pb_[2][2];
#pragma unroll
        for (int qt = 0; qt < 2; ++qt)
#pragma unroll
            for (int t = 0; t < 2; ++t)
#pragma unroll
                for (int w = 0; w < 4; ++w) {
                    float s0 = sacc[qt][t * 8 + 2 * w];
                    float s1 = sacc[qt][t * 8 + 2 * w + 1];
                    float e0 = __builtin_amdgcn_exp2f(s0);
                    float e1 = __builtin_amdgcn_exp2f(s1);
                    float p0 = (s0 == mthr) ? 0.f : e0;
                    float p1 = (s1 == mthr) ? 0.f : e1;
                    ps[qt] += p0 + p1;
                    ((f16x2*)(&pb_[qt][t]))[w] = cvt_pk(p0, p1);
                }

        // ---- PV ----
#pragma unroll
        for (int dt = 0; dt < 2; ++dt)
#pragma unroll
            for (int qt = 0; qt < 2; ++qt)
#pragma unroll
                for (int t = 0; t < 2; ++t)
                    oacc[dt][qt] = mfma32(av[dt][t], pb_[qt][t], oacc[dt][qt]);

        __builtin_amdgcn_sched_barrier(0);
        __builtin_amdgcn_s_barrier();             // all waves done with buf (it-1)&3
        __builtin_amdgcn_sched_barrier(0);
        if (it < 29) STAGE((it + 3) & 3, it + 3); // overwrite is now safe
    }
#undef STAGE

    // ---- epilogue: Sum(p) exchange + 4-way tree combine in recycled LDS ----
    ps[0] += __shfl_xor(ps[0], 32);
    ps[1] += __shfl_xor(ps[1], 32);
    if (lane < 32) { mlx[qg][s][0][lane] = ps[0]; mlx[qg][s][1][lane] = ps[1]; }
    __syncthreads();

    float* SC = (float*)smem;        // [qg*2+b][64 regs][64 lanes]
#define SCI(B, DT, QT, R) ((((qg * 2 + (B)) * 64) + ((DT) * 2 + (QT)) * 16 + (R)) * 64 + lane)
    if (s >= 2) {
#pragma unroll
        for (int dt = 0; dt < 2; ++dt)
#pragma unroll
            for (int qt = 0; qt < 2; ++qt)
#pragma unroll
                for (int r = 0; r < 16; ++r)
                    SC[SCI(s - 2, dt, qt, r)] = oacc[dt][qt][r];
    }
    __syncthreads();
    if (s < 2) {
#pragma unroll
        for (int dt = 0; dt < 2; ++dt)
#pragma unroll
            for (int qt = 0; qt < 2; ++qt)
#pragma unroll
                for (int r = 0; r < 16; ++r)
                    oacc[dt][qt][r] += SC[SCI(s, dt, qt, r)];
        if (s == 1) {
#pragma unroll
            for (int dt = 0; dt < 2; ++dt)
#pragma unroll
                for (int qt = 0; qt < 2; ++qt)
#pragma unroll
                    for (int r = 0; r < 16; ++r)
                        SC[SCI(1, dt, qt, r)] = oacc[dt][qt][r];
        }
    }
    __syncthreads();
    if (s == 0) {
        float inv[2];
#pragma unroll
        for (int qt = 0; qt < 2; ++qt)
            inv[qt] = 1.0f / (mlx[qg][0][qt][l31] + mlx[qg][1][qt][l31] +
                              mlx[qg][2][qt][l31] + mlx[qg][3][qt][l31]);
#pragma unroll
        for (int qt = 0; qt < 2; ++qt) {
            float* o0 = out + ((size_t)batch * 4096 + q0 + qt * 32 + l31) * 64;
#pragma unroll
            for (int dt = 0; dt < 2; ++dt)
#pragma unroll
                for (int rg = 0; rg < 4; ++rg) {  // reg r=rg*4+j -> d = dt*32+rg*8+hi*4+j
                    float4 v;
                    v.x = (oacc[dt][qt][rg * 4 + 0] + SC[SCI(1, dt, qt, rg * 4 + 0)]) * inv[qt];
                    v.y = (oacc[dt][qt][rg * 4 + 1] + SC[SCI(1, dt, qt, rg * 4 + 1)]) * inv[qt];
                    v.z = (oacc[dt][qt][rg * 4 + 2] + SC[SCI(1, dt, qt, rg * 4 + 2)]) * inv[qt];
                    v.w = (oacc[dt][qt][rg * 4 + 3] + SC[SCI(1, dt, qt, rg * 4 + 3)]) * inv[qt];
                    *(float4*)(o0 + dt * 32 + rg * 8 + hi2 * 4) = v;
                }
        }
    }
#undef SCI
}

// ---------------------------------------------------------------------------
extern "C" void kernel_launch(void* const* d_in, const int* in_sizes, int n_in,
                              void* d_out, int out_size, void* d_ws, size_t ws_size,
                              hipStream_t stream) {
    const float* q  = (const float*)d_in[0];
    const float* k  = (const float*)d_in[1];
    const float* v  = (const float*)d_in[2];
    const float* Wq = (const float*)d_in[3];
    const float* bq = (const float*)d_in[4];
    const float* Wk = (const float*)d_in[5];
    const float* bk = (const float*)d_in[6];
    const float* Wv = (const float*)d_in[7];
    const float* bv = (const float*)d_in[8];
    const int* mask = (const int*)d_in[9];
    float* out = (float*)d_out;

    const size_t NTOK = (size_t)8 * 4096;      // 32768 rows
    f16* qp  = (f16*)d_ws;                     // [8][4096][64]  (pre-scaled by QSC)
    f16* kp  = qp + NTOK * 64;                 // [8][4096][64]
    f16* vpT = kp + NTOK * 64;                 // [8][64][4096]
    f16* WT  = vpT + NTOK * 64;                // [3][64][512]

    ah_wt_prep<<<dim3(3), 256, 0, stream>>>(Wq, Wk, Wv, WT);
    ah_proj<<<dim3(512, 3), 256, 0, stream>>>(q, k, v, bq, bk, bv, WT, qp, kp, vpT);
    ah_attn<<<dim3(256), 512, 0, stream>>>(qp, kp, vpT, mask, out);
}